// Round 15
// baseline (1042.142 us; speedup 1.0000x reference)
//
#include <hip/hip_runtime.h>

typedef unsigned short u16;
typedef unsigned int u32;
typedef __bf16 bf16x8 __attribute__((ext_vector_type(8)));
typedef u16 u16x8 __attribute__((ext_vector_type(8)));
typedef float f32x4 __attribute__((ext_vector_type(4)));

#define KOFF 27
#define KPAD 28
#define EPSV 1e-5f
#define FRAGS_PER_CONV 14336  // 28 k-slots * 512 fragments (u16x8 units)
#define LDS_S 133             // LDS row stride (ints) for prep_tcidx

__device__ __forceinline__ u16 f2bf(float f) {
  u32 u = __builtin_bit_cast(u32, f);
  u = (u + 0x7FFFu + ((u >> 16) & 1u)) >> 16;
  return (u16)u;
}
__device__ __forceinline__ float bf2f(u16 h) {
  return __builtin_bit_cast(float, (u32)h << 16);
}

// async copy: per-lane global src, LDS dest = uniform base + lane*16, no VGPR dest
__device__ __forceinline__ void gl_lds16(const void* g, void* l) {
  __builtin_amdgcn_global_load_lds(
      (__attribute__((address_space(1))) void*)g,
      (__attribute__((address_space(3))) void*)l, 16, 0, 0);
}

// ---- x (f32) -> bf16, vectorized ----
__global__ void prep_x(const float* __restrict__ x, u16* __restrict__ xg, int n8) {
  int stride = gridDim.x * blockDim.x;
  for (int i = blockIdx.x * blockDim.x + threadIdx.x; i < n8; i += stride) {
    const f32x4* p = reinterpret_cast<const f32x4*>(x) + i * 2;
    f32x4 v0 = p[0], v1 = p[1];
    u16x8 o;
    o[0] = f2bf(v0[0]); o[1] = f2bf(v0[1]); o[2] = f2bf(v0[2]); o[3] = f2bf(v0[3]);
    o[4] = f2bf(v1[0]); o[5] = f2bf(v1[1]); o[6] = f2bf(v1[2]); o[7] = f2bf(v1[3]);
    reinterpret_cast<u16x8*>(xg)[i] = o;
  }
}

// ---- nbr+mask -> tile-major cidx_t[tile][28][16]; -1 = skip; k=27 is pad ----
__global__ __launch_bounds__(256) void prep_tcidx(
    const int* __restrict__ nbr, const int* __restrict__ msk,
    int* __restrict__ cidx_t) {
  __shared__ int lds[27 * LDS_S + 16];
  const int tid = threadIdx.x;
  const int blk = blockIdx.x;
  const int in_base = blk * (128 * KOFF);
#pragma unroll
  for (int it = 0; it < 14; it++) {
    int t = tid + it * 256;
    if (t < 128 * KOFF) {
      int g = in_base + t;
      int v = msk[g] ? nbr[g] : -1;
      int row = (u32)t / KOFF;
      int k = t - row * KOFF;
      lds[k * LDS_S + row] = v;
    }
  }
  __syncthreads();
  const int out_base = blk * (8 * KPAD * 16);
#pragma unroll
  for (int it = 0; it < 14; it++) {
    int o = tid + it * 256;
    int tl = (u32)o / (KPAD * 16);
    int rem = o - tl * (KPAD * 16);
    int k = rem >> 4;
    int r = rem & 15;
    int v = (k < KOFF) ? lds[k * LDS_S + tl * 16 + r] : -1;
    cidx_t[out_base + o] = v;
  }
}

// ---- W1,W2 -> bf16 B-fragments in MFMA lane order; k-slot 27 zeroed ----
__global__ void prep_w(const float* __restrict__ W1, const float* __restrict__ W2,
                       u16* __restrict__ wf) {
  int tid = blockIdx.x * blockDim.x + threadIdx.x;
  if (tid >= 2 * FRAGS_PER_CONV) return;
  int conv = tid / FRAGS_PER_CONV;
  int slot = tid - conv * FRAGS_PER_CONV;
  int k = slot >> 9;
  u16x8 o;
  if (k >= KOFF) {
#pragma unroll
    for (int j = 0; j < 8; j++) o[j] = 0;
  } else {
    const float* src = conv ? W2 : W1;
    int rest = slot & 511;
    int c = rest >> 8;
    int nt = (rest >> 6) & 3;
    int lane = rest & 63;
    int col = nt * 16 + (lane & 15);
    int kk0 = c * 32 + (lane >> 4) * 8;
    int base = k * 4096 + kk0 * 64 + col;
#pragma unroll
    for (int j = 0; j < 8; j++) o[j] = f2bf(src[base + j * 64]);
  }
  reinterpret_cast<u16x8*>(wf)[tid] = o;
}

// ---- sparse conv: r12 structure (4 tiles/wave, conditional VGPR gathers,
// block-shared B in LDS, launch_bounds(256,4)) with PAIRED-k staging: stage
// B for two k-slots (16KB) per barrier -> 14 barriers/drains instead of 27,
// and B[pair t+1] gets two k-steps of latency cover. Slot 27 = zero pad. ----
__global__ __launch_bounds__(256, 4) void sconv(
    const u16* __restrict__ xg, const int* __restrict__ cidx_t,
    const u16* __restrict__ wf, u16* __restrict__ hout,
    float* __restrict__ psum, float* __restrict__ psq) {
  __shared__ __align__(1024) bf16x8 bsm[2][1024];  // 2 x 16KB (one k-PAIR each)
  const int lane = threadIdx.x & 63;
  const int r = lane & 15;        // A row within tile / C col within 16-group
  const int kg = lane >> 4;       // channel-group
  const int widInBlk = threadIdx.x >> 6;
  const int waveId = blockIdx.x * 4 + widInBlk;   // grid exact: no guard (barriers)
  const char* wfc = (const char*)wf;
  const int chOff = kg * 8;
  bf16x8 zz;
#pragma unroll
  for (int j = 0; j < 8; j++) zz[j] = (__bf16)0.0f;

  const int n0 = waveId * 64;
  const int* cp[4];
#pragma unroll
  for (int j = 0; j < 4; j++)
    cp[j] = cidx_t + (size_t)(waveId * 4 + j) * (KPAD * 16) + r;

  f32x4 acc[4][4];  // [tile][nt], constant indexing only
#pragma unroll
  for (int j = 0; j < 4; j++)
#pragma unroll
    for (int nt = 0; nt < 4; nt++) {
      acc[j][nt][0] = 0.f; acc[j][nt][1] = 0.f;
      acc[j][nt][2] = 0.f; acc[j][nt][3] = 0.f;
    }

// block-cooperative stage of k-pair tp (16KB = wf slots 2tp, 2tp+1, contiguous)
#define STAGEB2(bc, tp)                                                       \
  {                                                                           \
    const char* s = wfc + ((size_t)(tp) << 14) + widInBlk * 1024 + lane * 16; \
    char* d = (char*)&bsm[bc][0] + widInBlk * 1024 + lane * 16;               \
    gl_lds16(s, d);                                                           \
    gl_lds16(s + 4096, d + 4096);                                             \
    gl_lds16(s + 8192, d + 8192);                                             \
    gl_lds16(s + 12288, d + 12288);                                           \
  }

// one k-slot: conditional gathers + 32 MFMAs reading B from bl
#define KSECT(K, bl)                                                          \
  {                                                                           \
    int id[4];                                                                \
    _Pragma("unroll") for (int j = 0; j < 4; j++) id[j] = cp[j][(K) << 4];    \
    bf16x8 a0[4], a1[4];                                                      \
    _Pragma("unroll") for (int j = 0; j < 4; j++) {                           \
      a0[j] = zz; a1[j] = zz;                                                 \
      if (id[j] >= 0) {                                                       \
        const bf16x8* ap =                                                    \
            reinterpret_cast<const bf16x8*>(xg + ((size_t)id[j] << 6) + chOff); \
        a0[j] = ap[0];                                                        \
        a1[j] = ap[4];                                                        \
      }                                                                       \
    }                                                                         \
    _Pragma("unroll") for (int nt = 0; nt < 4; nt++) {                        \
      bf16x8 b = (bl)[nt * 64 + lane];                                        \
      _Pragma("unroll") for (int j = 0; j < 4; j++)                           \
        acc[j][nt] = __builtin_amdgcn_mfma_f32_16x16x32_bf16(a0[j], b, acc[j][nt], 0, 0, 0); \
    }                                                                         \
    _Pragma("unroll") for (int nt = 0; nt < 4; nt++) {                        \
      bf16x8 b = (bl)[256 + nt * 64 + lane];                                  \
      _Pragma("unroll") for (int j = 0; j < 4; j++)                           \
        acc[j][nt] = __builtin_amdgcn_mfma_f32_16x16x32_bf16(a1[j], b, acc[j][nt], 0, 0, 0); \
    }                                                                         \
  }

  STAGEB2(0, 0);  // prologue: pair 0 (k=0,1) in flight

  for (int t = 0; t < 14; t++) {
    // drain our stage ops, then block-sync so all 4 waves' stage is visible.
    asm volatile("s_waitcnt vmcnt(0)" ::: "memory");
    __syncthreads();
    if (t + 1 < 14) STAGEB2((t + 1) & 1, t + 1);  // async, no dest regs

    const bf16x8* bl = &bsm[t & 1][0];
    KSECT(2 * t, bl);            // k0
    KSECT(2 * t + 1, bl + 512);  // k1 (t=13 -> pad slot: gathers skipped, B=0)
  }
#undef KSECT
#undef STAGEB2

  // C/D layout: col = lane&15 (+16*nt), row = kg*4 + reg (+16*tile)
  float ssum[4] = {0.f, 0.f, 0.f, 0.f};
  float ssq[4] = {0.f, 0.f, 0.f, 0.f};
#pragma unroll
  for (int j = 0; j < 4; j++) {
#pragma unroll
    for (int nt = 0; nt < 4; nt++) {
      const int col = nt * 16 + r;
      float rs = 0.f, rq = 0.f;
#pragma unroll
      for (int reg = 0; reg < 4; reg++) {
        float v = acc[j][nt][reg];
        rs += v;
        rq += v * v;
        hout[(size_t)(n0 + j * 16 + kg * 4 + reg) * 64 + col] = f2bf(v);
      }
      ssum[nt] += rs;
      ssq[nt] += rq;
    }
  }
#pragma unroll
  for (int nt = 0; nt < 4; nt++) {
    ssum[nt] += __shfl_xor(ssum[nt], 16, 64);
    ssum[nt] += __shfl_xor(ssum[nt], 32, 64);
    ssq[nt] += __shfl_xor(ssq[nt], 16, 64);
    ssq[nt] += __shfl_xor(ssq[nt], 32, 64);
  }
  if (lane < 16) {
#pragma unroll
    for (int nt = 0; nt < 4; nt++) {
      psum[(size_t)waveId * 64 + nt * 16 + lane] = ssum[nt];
      psq[(size_t)waveId * 64 + nt * 16 + lane] = ssq[nt];
    }
  }
}

// ---- finalize BN: one block per channel ----
__global__ void bn_finalize(const float* __restrict__ psum, const float* __restrict__ psq,
                            const float* __restrict__ g, const float* __restrict__ b,
                            float* __restrict__ scale, float* __restrict__ shift,
                            float invN, int nw) {
  int c = blockIdx.x;
  float s = 0.f, q = 0.f;
  for (int i = threadIdx.x; i < nw; i += blockDim.x) {
    s += psum[(size_t)i * 64 + c];
    q += psq[(size_t)i * 64 + c];
  }
#pragma unroll
  for (int off = 32; off >= 1; off >>= 1) {
    s += __shfl_down(s, off, 64);
    q += __shfl_down(q, off, 64);
  }
  __shared__ float ls[4], lq[4];
  int wid = threadIdx.x >> 6;
  int lane = threadIdx.x & 63;
  if (lane == 0) { ls[wid] = s; lq[wid] = q; }
  __syncthreads();
  if (threadIdx.x == 0) {
    s = ls[0] + ls[1] + ls[2] + ls[3];
    q = lq[0] + lq[1] + lq[2] + lq[3];
    float mean = s * invN;
    float var = q * invN - mean * mean;
    float rstd = rsqrtf(var + EPSV);
    float sc = rstd * g[c];
    scale[c] = sc;
    shift[c] = b[c] - mean * sc;
  }
}

// ---- y = relu(h*scale + shift) (bf16 -> bf16) ----
__global__ void bn_relu_apply(const u16* __restrict__ h, const float* __restrict__ scale,
                              const float* __restrict__ shift, u16* __restrict__ y, int n8) {
  int i0 = blockIdx.x * blockDim.x + threadIdx.x;
  int c0 = (i0 * 8) & 63;
  float sc[8], sh[8];
#pragma unroll
  for (int j = 0; j < 8; j++) { sc[j] = scale[c0 + j]; sh[j] = shift[c0 + j]; }
  int stride = gridDim.x * blockDim.x;  // stride*8 multiple of 64 -> c0 invariant
  for (int i = i0; i < n8; i += stride) {
    u16x8 hv = reinterpret_cast<const u16x8*>(h)[i];
    u16x8 o;
#pragma unroll
    for (int j = 0; j < 8; j++) {
      float f = bf2f(hv[j]) * sc[j] + sh[j];
      o[j] = f2bf(fmaxf(f, 0.f));
    }
    reinterpret_cast<u16x8*>(y)[i] = o;
  }
}

// ---- out = relu(h*scale + shift + x) (f32 out) ----
__global__ void bn_add_relu(const u16* __restrict__ h, const float* __restrict__ scale,
                            const float* __restrict__ shift, const float* __restrict__ x,
                            float* __restrict__ out, int n8) {
  int i0 = blockIdx.x * blockDim.x + threadIdx.x;
  int c0 = (i0 * 8) & 63;
  float sc[8], sh[8];
#pragma unroll
  for (int j = 0; j < 8; j++) { sc[j] = scale[c0 + j]; sh[j] = shift[c0 + j]; }
  int stride = gridDim.x * blockDim.x;
  for (int i = i0; i < n8; i += stride) {
    u16x8 hv = reinterpret_cast<const u16x8*>(h)[i];
    const f32x4* xp = reinterpret_cast<const f32x4*>(x) + i * 2;
    f32x4 x0 = xp[0], x1 = xp[1];
    f32x4 o0, o1;
#pragma unroll
    for (int j = 0; j < 4; j++) {
      o0[j] = fmaxf(bf2f(hv[j]) * sc[j] + sh[j] + x0[j], 0.f);
      o1[j] = fmaxf(bf2f(hv[j + 4]) * sc[j + 4] + sh[j + 4] + x1[j], 0.f);
    }
    f32x4* op = reinterpret_cast<f32x4*>(out) + i * 2;
    op[0] = o0;
    op[1] = o1;
  }
}

extern "C" void kernel_launch(void* const* d_in, const int* in_sizes, int n_in,
                              void* d_out, int out_size, void* d_ws, size_t ws_size,
                              hipStream_t stream) {
  const float* x = (const float*)d_in[0];
  const int* nbr = (const int*)d_in[1];
  const int* msk = (const int*)d_in[2];
  const float* W1 = (const float*)d_in[3];
  const float* g1 = (const float*)d_in[4];
  const float* b1 = (const float*)d_in[5];
  const float* W2 = (const float*)d_in[6];
  const float* g2 = (const float*)d_in[7];
  const float* b2 = (const float*)d_in[8];
  float* out = (float*)d_out;

  const int N = in_sizes[0] / 64;     // 800000
  const int nquads = N / 64;          // 12500 waves, 1 quad (64 rows) each
  const int nblocks = nquads / 4;     // 3125 blocks of 4 waves (grid exact)
  const int n8 = N * 8;
  const size_t NC2 = (size_t)N * 64 * 2;      // one bf16 feature map
  const size_t MAPB = NC2 + 256;

  char* ws = (char*)d_ws;
  u16* bufA = (u16*)ws;                       // xg, then y1
  u16* bufB = (u16*)(ws + MAPB);              // h1, then h2
  u16* wf = (u16*)(ws + 2 * MAPB);            // 2 * 229376 B of B-fragments
  float* psum = (float*)(ws + 2 * MAPB + 512 * 1024);
  float* psq = psum + (size_t)nquads * 64;
  float* sc = psq + (size_t)nquads * 64;      // scale1|shift1|scale2|shift2

  // cidx_t ([N/16][28][16] ints, 89.6 MB) lives in d_out: dead until
  // bn_add_relu, which runs last and fully overwrites d_out.
  int* cidx_t = (int*)d_out;

  float invN = 1.0f / (float)N;

  prep_x<<<2048, 256, 0, stream>>>(x, bufA, n8);
  prep_tcidx<<<N / 128, 256, 0, stream>>>(nbr, msk, cidx_t);
  prep_w<<<112, 256, 0, stream>>>(W1, W2, wf);
  sconv<<<nblocks, 256, 0, stream>>>(bufA, cidx_t, wf, bufB, psum, psq);
  bn_finalize<<<64, 256, 0, stream>>>(psum, psq, g1, b1, sc, sc + 64, invN, nquads);
  bn_relu_apply<<<2048, 256, 0, stream>>>(bufB, sc, sc + 64, bufA, n8);
  sconv<<<nblocks, 256, 0, stream>>>(bufA, cidx_t, wf + FRAGS_PER_CONV * 8, bufB, psum, psq);
  bn_finalize<<<64, 256, 0, stream>>>(psum, psq, g2, b2, sc + 128, sc + 192, invN, nquads);
  bn_add_relu<<<2048, 256, 0, stream>>>(bufB, sc + 128, sc + 192, x, out, n8);
}

// Round 16
// 839.916 us; speedup vs baseline: 1.2408x; 1.2408x over previous
//
#include <hip/hip_runtime.h>

typedef unsigned short u16;
typedef unsigned int u32;
typedef __bf16 bf16x8 __attribute__((ext_vector_type(8)));
typedef u16 u16x8 __attribute__((ext_vector_type(8)));
typedef float f32x4 __attribute__((ext_vector_type(4)));

#define KOFF 27
#define KPAD 28
#define EPSV 1e-5f
#define FRAGS_PER_CONV 14336  // 28 k-slots * 512 fragments (u16x8 units)
#define LDS_S 133             // LDS row stride (ints) for prep_tcidx

__device__ __forceinline__ u16 f2bf(float f) {
  u32 u = __builtin_bit_cast(u32, f);
  u = (u + 0x7FFFu + ((u >> 16) & 1u)) >> 16;
  return (u16)u;
}
__device__ __forceinline__ float bf2f(u16 h) {
  return __builtin_bit_cast(float, (u32)h << 16);
}

// async copy: per-lane global src, LDS dest = uniform base + lane*16, no VGPR dest
__device__ __forceinline__ void gl_lds16(const void* g, void* l) {
  __builtin_amdgcn_global_load_lds(
      (__attribute__((address_space(1))) void*)g,
      (__attribute__((address_space(3))) void*)l, 16, 0, 0);
}

// ---- x (f32) -> bf16, vectorized ----
__global__ void prep_x(const float* __restrict__ x, u16* __restrict__ xg, int n8) {
  int stride = gridDim.x * blockDim.x;
  for (int i = blockIdx.x * blockDim.x + threadIdx.x; i < n8; i += stride) {
    const f32x4* p = reinterpret_cast<const f32x4*>(x) + i * 2;
    f32x4 v0 = p[0], v1 = p[1];
    u16x8 o;
    o[0] = f2bf(v0[0]); o[1] = f2bf(v0[1]); o[2] = f2bf(v0[2]); o[3] = f2bf(v0[3]);
    o[4] = f2bf(v1[0]); o[5] = f2bf(v1[1]); o[6] = f2bf(v1[2]); o[7] = f2bf(v1[3]);
    reinterpret_cast<u16x8*>(xg)[i] = o;
  }
}

// ---- nbr+mask -> quad-major packed cidx_q[quad][28][16][4]; -1 = skip ----
// int4 at (quad,k,r) = indices of the 4 tiles in the quad -> one dwordx4
// load per k-step in sconv. Block = 128 rows (2 quads), coalesced both ends.
__global__ __launch_bounds__(256) void prep_tcidx(
    const int* __restrict__ nbr, const int* __restrict__ msk,
    int* __restrict__ cidx_q) {
  __shared__ int lds[27 * LDS_S + 16];
  const int tid = threadIdx.x;
  const int blk = blockIdx.x;
  const int in_base = blk * (128 * KOFF);
#pragma unroll
  for (int it = 0; it < 14; it++) {
    int t = tid + it * 256;
    if (t < 128 * KOFF) {
      int g = in_base + t;
      int v = msk[g] ? nbr[g] : -1;
      int row = (u32)t / KOFF;
      int k = t - row * KOFF;
      lds[k * LDS_S + row] = v;
    }
  }
  __syncthreads();
  // write 2 quads * 28 * 16 * 4 = 3584 ints, coalesced
  const int out_base = blk * (2 * KPAD * 64);
#pragma unroll
  for (int it = 0; it < 14; it++) {
    int o = tid + it * 256;
    int q = (u32)o / (KPAD * 64);
    int rem = o - q * (KPAD * 64);
    int k = rem >> 6;
    int sub = rem & 63;
    int r = sub >> 2;
    int j = sub & 3;
    int v = (k < KOFF) ? lds[k * LDS_S + q * 64 + j * 16 + r] : -1;
    cidx_q[out_base + o] = v;
  }
}

// ---- W1,W2 -> bf16 B-fragments in MFMA lane order; k-slot 27 zeroed ----
__global__ void prep_w(const float* __restrict__ W1, const float* __restrict__ W2,
                       u16* __restrict__ wf) {
  int tid = blockIdx.x * blockDim.x + threadIdx.x;
  if (tid >= 2 * FRAGS_PER_CONV) return;
  int conv = tid / FRAGS_PER_CONV;
  int slot = tid - conv * FRAGS_PER_CONV;
  int k = slot >> 9;
  u16x8 o;
  if (k >= KOFF) {
#pragma unroll
    for (int j = 0; j < 8; j++) o[j] = 0;
  } else {
    const float* src = conv ? W2 : W1;
    int rest = slot & 511;
    int c = rest >> 8;
    int nt = (rest >> 6) & 3;
    int lane = rest & 63;
    int col = nt * 16 + (lane & 15);
    int kk0 = c * 32 + (lane >> 4) * 8;
    int base = k * 4096 + kk0 * 64 + col;
#pragma unroll
    for (int j = 0; j < 8; j++) o[j] = f2bf(src[base + j * 64]);
  }
  reinterpret_cast<u16x8*>(wf)[tid] = o;
}

// ---- sparse conv: r12 structure (4 tiles/wave, conditional VGPR gathers,
// block-shared double-buffered B in LDS, launch_bounds(256,4)) with packed
// int4 index loads: one dwordx4 per k-step replaces 4 scalar idx loads and
// ~8-10 VGPRs of addressing -> fits the (256,4) cap without spill. ----
__global__ __launch_bounds__(256, 4) void sconv(
    const u16* __restrict__ xg, const int* __restrict__ cidx_q,
    const u16* __restrict__ wf, u16* __restrict__ hout,
    float* __restrict__ psum, float* __restrict__ psq) {
  __shared__ __align__(1024) bf16x8 bsm[2][512];  // 2 x 8KB B double-buffer
  const int lane = threadIdx.x & 63;
  const int r = lane & 15;        // A row within tile / C col within 16-group
  const int kg = lane >> 4;       // channel-group
  const int widInBlk = threadIdx.x >> 6;
  const int waveId = blockIdx.x * 4 + widInBlk;   // grid exact: no guard (barriers)
  const char* wfc = (const char*)wf;
  const int chOff = kg * 8;
  bf16x8 zz;
#pragma unroll
  for (int j = 0; j < 8; j++) zz[j] = (__bf16)0.0f;

  const int n0 = waveId * 64;
  // packed index stream: int4 at (waveId, k, r)
  const int4* cpq = reinterpret_cast<const int4*>(cidx_q) +
                    (size_t)waveId * (KPAD * 16) + r;

  f32x4 acc[4][4];  // [tile][nt], constant indexing only
#pragma unroll
  for (int j = 0; j < 4; j++)
#pragma unroll
    for (int nt = 0; nt < 4; nt++) {
      acc[j][nt][0] = 0.f; acc[j][nt][1] = 0.f;
      acc[j][nt][2] = 0.f; acc[j][nt][3] = 0.f;
    }

// block-cooperative stage of B[ks] (8KB) into buffer bc: per wave 2 x 1KB
#define STAGEB(bc, ks)                                                     \
  {                                                                        \
    const char* s = wfc + ((size_t)(ks) << 13) + widInBlk * 1024 + lane * 16; \
    char* d = (char*)&bsm[bc][0] + widInBlk * 1024 + lane * 16;            \
    gl_lds16(s, d);                                                        \
    gl_lds16(s + 4096, d + 4096);                                          \
  }

  STAGEB(0, 0);  // prologue: B[0] in flight

  for (int k = 0; k < KOFF; k++) {
    // drain our stage ops (gathers from k-1 already consumed by MFMAs),
    // then block-sync so all 4 waves' stage of B[k] is visible.
    asm volatile("s_waitcnt vmcnt(0)" ::: "memory");
    __syncthreads();
    if (k + 1 < KOFF) STAGEB((k + 1) & 1, k + 1);  // async, no dest regs

    int4 id4 = cpq[k << 4];
    bf16x8 a0[4], a1[4];
#pragma unroll
    for (int j = 0; j < 4; j++) { a0[j] = zz; a1[j] = zz; }
    if (id4.x >= 0) {
      const bf16x8* ap = reinterpret_cast<const bf16x8*>(xg + ((size_t)id4.x << 6) + chOff);
      a0[0] = ap[0]; a1[0] = ap[4];
    }
    if (id4.y >= 0) {
      const bf16x8* ap = reinterpret_cast<const bf16x8*>(xg + ((size_t)id4.y << 6) + chOff);
      a0[1] = ap[0]; a1[1] = ap[4];
    }
    if (id4.z >= 0) {
      const bf16x8* ap = reinterpret_cast<const bf16x8*>(xg + ((size_t)id4.z << 6) + chOff);
      a0[2] = ap[0]; a1[2] = ap[4];
    }
    if (id4.w >= 0) {
      const bf16x8* ap = reinterpret_cast<const bf16x8*>(xg + ((size_t)id4.w << 6) + chOff);
      a0[3] = ap[0]; a1[3] = ap[4];
    }
    const bf16x8* bl = &bsm[k & 1][0];
#pragma unroll
    for (int nt = 0; nt < 4; nt++) {
      bf16x8 b = bl[nt * 64 + lane];
#pragma unroll
      for (int j = 0; j < 4; j++)
        acc[j][nt] = __builtin_amdgcn_mfma_f32_16x16x32_bf16(a0[j], b, acc[j][nt], 0, 0, 0);
    }
#pragma unroll
    for (int nt = 0; nt < 4; nt++) {
      bf16x8 b = bl[256 + nt * 64 + lane];
#pragma unroll
      for (int j = 0; j < 4; j++)
        acc[j][nt] = __builtin_amdgcn_mfma_f32_16x16x32_bf16(a1[j], b, acc[j][nt], 0, 0, 0);
    }
  }
#undef STAGEB

  // C/D layout: col = lane&15 (+16*nt), row = kg*4 + reg (+16*tile)
  float ssum[4] = {0.f, 0.f, 0.f, 0.f};
  float ssq[4] = {0.f, 0.f, 0.f, 0.f};
#pragma unroll
  for (int j = 0; j < 4; j++) {
#pragma unroll
    for (int nt = 0; nt < 4; nt++) {
      const int col = nt * 16 + r;
      float rs = 0.f, rq = 0.f;
#pragma unroll
      for (int reg = 0; reg < 4; reg++) {
        float v = acc[j][nt][reg];
        rs += v;
        rq += v * v;
        hout[(size_t)(n0 + j * 16 + kg * 4 + reg) * 64 + col] = f2bf(v);
      }
      ssum[nt] += rs;
      ssq[nt] += rq;
    }
  }
#pragma unroll
  for (int nt = 0; nt < 4; nt++) {
    ssum[nt] += __shfl_xor(ssum[nt], 16, 64);
    ssum[nt] += __shfl_xor(ssum[nt], 32, 64);
    ssq[nt] += __shfl_xor(ssq[nt], 16, 64);
    ssq[nt] += __shfl_xor(ssq[nt], 32, 64);
  }
  if (lane < 16) {
#pragma unroll
    for (int nt = 0; nt < 4; nt++) {
      psum[(size_t)waveId * 64 + nt * 16 + lane] = ssum[nt];
      psq[(size_t)waveId * 64 + nt * 16 + lane] = ssq[nt];
    }
  }
}

// ---- finalize BN: one block per channel ----
__global__ void bn_finalize(const float* __restrict__ psum, const float* __restrict__ psq,
                            const float* __restrict__ g, const float* __restrict__ b,
                            float* __restrict__ scale, float* __restrict__ shift,
                            float invN, int nw) {
  int c = blockIdx.x;
  float s = 0.f, q = 0.f;
  for (int i = threadIdx.x; i < nw; i += blockDim.x) {
    s += psum[(size_t)i * 64 + c];
    q += psq[(size_t)i * 64 + c];
  }
#pragma unroll
  for (int off = 32; off >= 1; off >>= 1) {
    s += __shfl_down(s, off, 64);
    q += __shfl_down(q, off, 64);
  }
  __shared__ float ls[4], lq[4];
  int wid = threadIdx.x >> 6;
  int lane = threadIdx.x & 63;
  if (lane == 0) { ls[wid] = s; lq[wid] = q; }
  __syncthreads();
  if (threadIdx.x == 0) {
    s = ls[0] + ls[1] + ls[2] + ls[3];
    q = lq[0] + lq[1] + lq[2] + lq[3];
    float mean = s * invN;
    float var = q * invN - mean * mean;
    float rstd = rsqrtf(var + EPSV);
    float sc = rstd * g[c];
    scale[c] = sc;
    shift[c] = b[c] - mean * sc;
  }
}

// ---- y = relu(h*scale + shift) (bf16 -> bf16) ----
__global__ void bn_relu_apply(const u16* __restrict__ h, const float* __restrict__ scale,
                              const float* __restrict__ shift, u16* __restrict__ y, int n8) {
  int i0 = blockIdx.x * blockDim.x + threadIdx.x;
  int c0 = (i0 * 8) & 63;
  float sc[8], sh[8];
#pragma unroll
  for (int j = 0; j < 8; j++) { sc[j] = scale[c0 + j]; sh[j] = shift[c0 + j]; }
  int stride = gridDim.x * blockDim.x;  // stride*8 multiple of 64 -> c0 invariant
  for (int i = i0; i < n8; i += stride) {
    u16x8 hv = reinterpret_cast<const u16x8*>(h)[i];
    u16x8 o;
#pragma unroll
    for (int j = 0; j < 8; j++) {
      float f = bf2f(hv[j]) * sc[j] + sh[j];
      o[j] = f2bf(fmaxf(f, 0.f));
    }
    reinterpret_cast<u16x8*>(y)[i] = o;
  }
}

// ---- out = relu(h*scale + shift + xg) (bf16 identity, f32 out) ----
__global__ void bn_add_relu(const u16* __restrict__ h, const float* __restrict__ scale,
                            const float* __restrict__ shift, const u16* __restrict__ xg,
                            float* __restrict__ out, int n8) {
  int i0 = blockIdx.x * blockDim.x + threadIdx.x;
  int c0 = (i0 * 8) & 63;
  float sc[8], sh[8];
#pragma unroll
  for (int j = 0; j < 8; j++) { sc[j] = scale[c0 + j]; sh[j] = shift[c0 + j]; }
  int stride = gridDim.x * blockDim.x;
  for (int i = i0; i < n8; i += stride) {
    u16x8 hv = reinterpret_cast<const u16x8*>(h)[i];
    u16x8 xv = reinterpret_cast<const u16x8*>(xg)[i];
    f32x4 o0, o1;
#pragma unroll
    for (int j = 0; j < 4; j++) {
      o0[j] = fmaxf(bf2f(hv[j]) * sc[j] + sh[j] + bf2f(xv[j]), 0.f);
      o1[j] = fmaxf(bf2f(hv[j + 4]) * sc[j + 4] + sh[j + 4] + bf2f(xv[j + 4]), 0.f);
    }
    f32x4* op = reinterpret_cast<f32x4*>(out) + i * 2;
    op[0] = o0;
    op[1] = o1;
  }
}

extern "C" void kernel_launch(void* const* d_in, const int* in_sizes, int n_in,
                              void* d_out, int out_size, void* d_ws, size_t ws_size,
                              hipStream_t stream) {
  const float* x = (const float*)d_in[0];
  const int* nbr = (const int*)d_in[1];
  const int* msk = (const int*)d_in[2];
  const float* W1 = (const float*)d_in[3];
  const float* g1 = (const float*)d_in[4];
  const float* b1 = (const float*)d_in[5];
  const float* W2 = (const float*)d_in[6];
  const float* g2 = (const float*)d_in[7];
  const float* b2 = (const float*)d_in[8];
  float* out = (float*)d_out;

  const int N = in_sizes[0] / 64;     // 800000
  const int nquads = N / 64;          // 12500 waves, 1 quad (64 rows) each
  const int nblocks = nquads / 4;     // 3125 blocks of 4 waves (grid exact)
  const int n8 = N * 8;
  const size_t NC2 = (size_t)N * 64 * 2;      // one bf16 feature map
  const size_t MAPB = NC2 + 256;

  char* ws = (char*)d_ws;
  u16* bufA = (u16*)ws;                       // xg (preserved for epilogue)
  u16* bufB = (u16*)(ws + MAPB);              // h1, then h2
  u16* wf = (u16*)(ws + 2 * MAPB);            // 2 * 229376 B of B-fragments
  float* psum = (float*)(ws + 2 * MAPB + 512 * 1024);
  float* psq = psum + (size_t)nquads * 64;
  float* sc = psq + (size_t)nquads * 64;      // scale1|shift1|scale2|shift2

  // dead d_out space (204.8 MB): cidx_q ints [0, 22.4M) = 89.6 MB; y1 map
  // (102.4 MB) right after. Both dead before bn_add_relu overwrites d_out.
  int* cidx_q = (int*)d_out;
  u16* y1 = (u16*)((char*)d_out + (size_t)N * KPAD * 4);

  float invN = 1.0f / (float)N;

  prep_x<<<2048, 256, 0, stream>>>(x, bufA, n8);
  prep_tcidx<<<N / 128, 256, 0, stream>>>(nbr, msk, cidx_q);
  prep_w<<<112, 256, 0, stream>>>(W1, W2, wf);
  sconv<<<nblocks, 256, 0, stream>>>(bufA, cidx_q, wf, bufB, psum, psq);
  bn_finalize<<<64, 256, 0, stream>>>(psum, psq, g1, b1, sc, sc + 64, invN, nquads);
  bn_relu_apply<<<2048, 256, 0, stream>>>(bufB, sc, sc + 64, y1, n8);
  sconv<<<nblocks, 256, 0, stream>>>(y1, cidx_q, wf + FRAGS_PER_CONV * 8, bufB, psum, psq);
  bn_finalize<<<64, 256, 0, stream>>>(psum, psq, g2, b2, sc + 128, sc + 192, invN, nquads);
  bn_add_relu<<<2048, 256, 0, stream>>>(bufB, sc + 128, sc + 192, bufA, out, n8);
}